// Round 3
// baseline (13464.882 us; speedup 1.0000x reference)
//
#include <hip/hip_runtime.h>

// ComplexLSTMLayer: B=32, T=1024, I=512, H=512
// Phase 1: X = Z2 @ Wz_comb  (bf16 MFMA GEMM, M=32768, N=2560, K=1024)
// Phase 2: ONE persistent kernel, 32 WGs (one per 16-h slab) x 512 threads.
//          Weights in registers. Cross-WG h/flag traffic via relaxed
//          agent-scope atomics (sc1, LLC-coherent) — NO cache-wide fences.

#define B_ 32
#define T_ 1024
#define Hd 512
#define Kd 1024        // 2*I = 2*H
#define Nd 2560        // 5*H
#define Md 32768       // B*T
#define HS_ELEMS 33554432ull  // B*T*H*2

typedef __attribute__((ext_vector_type(8))) short bf16x8;
typedef __attribute__((ext_vector_type(4))) float f32x4;

__device__ __forceinline__ unsigned short f_bf(float f) {
  unsigned int x; __builtin_memcpy(&x, &f, 4);
  unsigned int r = (x + 0x7FFFu + ((x >> 16) & 1u)) >> 16;  // RNE
  return (unsigned short)r;
}
__device__ __forceinline__ float bf_f(unsigned short u) {
  unsigned int i = ((unsigned int)u) << 16; float f; __builtin_memcpy(&f, &i, 4); return f;
}
__device__ __forceinline__ float fsig(float x) { return 1.0f / (1.0f + __expf(-x)); }
__device__ __forceinline__ void ctanh_(float zr, float zi, float& tr, float& ti) {
  float m2 = zr * zr + zi * zi + 1e-14f;
  float mag = __fsqrt_rn(m2);          // >= 1e-7, the ref's max(.,1e-8) never binds
  float e = __expf(2.0f * mag);
  float th = 1.0f - 2.0f / (e + 1.0f); // tanh(mag)
  float s = th / mag;
  tr = zr * s; ti = zi * s;
}

__device__ __forceinline__ void gl16(const unsigned short* g, unsigned short* l) {
  __builtin_amdgcn_global_load_lds(
      (const __attribute__((address_space(1))) void*)g,
      (__attribute__((address_space(3))) void*)l, 16, 0, 0);
}

__device__ __forceinline__ unsigned int ald(const unsigned int* p) {
  return __hip_atomic_load(p, __ATOMIC_RELAXED, __HIP_MEMORY_SCOPE_AGENT);
}
__device__ __forceinline__ void ast(unsigned int* p, unsigned int v) {
  __hip_atomic_store(p, v, __ATOMIC_RELAXED, __HIP_MEMORY_SCOPE_AGENT);
}

// ---------------------------------------------------------------------------
// Combined transposed weights [n][k] bf16 + combined bias.
// n = slab*80 + g*16 + (h%16); k = 2*j + p (p: 0=re,1=im)
// gates g: 0=i,1=f,2=o,3=cr,4=ci. i/f/o/cr: (+W0, -W1); ci: (+W1, +W0).
__global__ void build_weights(const float* Wzi, const float* Whi, const float* bi,
                              const float* Wzf, const float* Whf, const float* bfv,
                              const float* Wzc, const float* Whc, const float* bc,
                              const float* Wzo, const float* Who, const float* bo,
                              unsigned short* WzT, unsigned short* WhT, float* bcomb) {
  int n = blockIdx.x;
  int slab = n / 80, wi = n % 80, g = wi / 16, hh = slab * 16 + (wi & 15);
  const float *Wz, *Wh;
  if (g == 0)      { Wz = Wzi; Wh = Whi; }
  else if (g == 1) { Wz = Wzf; Wh = Whf; }
  else if (g == 2) { Wz = Wzo; Wh = Who; }
  else             { Wz = Wzc; Wh = Whc; }
  int q0, q1; float s0, s1;
  if (g < 4) { q0 = 0; s0 = 1.f; q1 = 1; s1 = -1.f; }
  else       { q0 = 1; s0 = 1.f; q1 = 0; s1 =  1.f; }
  for (int k = threadIdx.x; k < Kd; k += 256) {
    int j = k >> 1, p = k & 1;
    int q = p ? q1 : q0; float sg = p ? s1 : s0;
    WzT[(size_t)n * Kd + k] = f_bf(sg * Wz[(j * Hd + hh) * 2 + q]);
    WhT[(size_t)n * Kd + k] = f_bf(sg * Wh[(j * Hd + hh) * 2 + q]);
  }
  if (threadIdx.x == 0) {
    float bv;
    if (g == 0) bv = bi[hh]; else if (g == 1) bv = bfv[hh];
    else if (g == 2) bv = bo[hh];
    else if (g == 3) bv = bc[2 * hh]; else bv = bc[2 * hh + 1];
    bcomb[n] = bv;
  }
}

__global__ void cvt_z(const float4* __restrict__ z, ushort4* __restrict__ Z2) {
  for (size_t i = (size_t)blockIdx.x * 256 + threadIdx.x; i < 8388608ull; i += 8192ull * 256) {
    float4 v = z[i];
    ushort4 o;
    o.x = f_bf(v.x); o.y = f_bf(v.y); o.z = f_bf(v.z); o.w = f_bf(v.w);
    Z2[i] = o;
  }
}

// ---------------------------------------------------------------------------
// Phase-1 GEMM: X[m][n] = sum_k Z2[m][k] * WT[n][k]. bf16 out. (verified r1)
__global__ __launch_bounds__(256) void gemm_x(const unsigned short* __restrict__ Z2,
                                              const unsigned short* __restrict__ WT,
                                              unsigned short* __restrict__ X) {
  __shared__ unsigned short As[128 * 64];
  __shared__ unsigned short Bs[128 * 64];
  int tid = threadIdx.x, lane = tid & 63, wv = tid >> 6;
  int bid = blockIdx.x;
  int mb = bid / (Nd / 128), nb = bid % (Nd / 128);
  size_t m0 = (size_t)mb * 128, n0 = (size_t)nb * 128;
  int wr = wv >> 1, wc = wv & 1;
  int l15 = lane & 15, kg = lane >> 4;
  int lrow = tid >> 3;
  int lcol = (tid & 7) * 8;
  f32x4 acc[4][4] = {};
  for (int k0 = 0; k0 < Kd; k0 += 64) {
    __syncthreads();
#pragma unroll
    for (int c = 0; c < 4; ++c) {
      gl16(Z2 + (m0 + c * 32 + lrow) * Kd + k0 + lcol,
           As + (size_t)c * 2048 + wv * 512);
      gl16(WT + (n0 + c * 32 + lrow) * Kd + k0 + lcol,
           Bs + (size_t)c * 2048 + wv * 512);
    }
    __syncthreads();
#pragma unroll
    for (int ks = 0; ks < 2; ++ks) {
      int kk = ks * 32 + kg * 8;
      bf16x8 a[4], b[4];
#pragma unroll
      for (int i = 0; i < 4; ++i)
        a[i] = *reinterpret_cast<const bf16x8*>(&As[(wr * 64 + i * 16 + l15) * 64 + kk]);
#pragma unroll
      for (int j = 0; j < 4; ++j)
        b[j] = *reinterpret_cast<const bf16x8*>(&Bs[(wc * 64 + j * 16 + l15) * 64 + kk]);
#pragma unroll
      for (int i = 0; i < 4; ++i)
#pragma unroll
        for (int j = 0; j < 4; ++j)
          acc[i][j] = __builtin_amdgcn_mfma_f32_16x16x32_bf16(a[i], b[j], acc[i][j], 0, 0, 0);
    }
  }
#pragma unroll
  for (int i = 0; i < 4; ++i)
#pragma unroll
    for (int j = 0; j < 4; ++j) {
      size_t gm = m0 + wr * 64 + i * 16 + kg * 4;
      size_t gn = n0 + wc * 64 + j * 16 + l15;
#pragma unroll
      for (int r = 0; r < 4; ++r)
        X[(gm + r) * Nd + gn] = f_bf(acc[i][j][r]);
    }
}

// ---------------------------------------------------------------------------
// Persistent recurrence. WG s owns h-slab [s*16,(s+1)*16). 8 waves:
//   kh = wv>>1 (K quarter, 256 k), mh = wv&1 (batch half, 16 rows).
// All cross-WG traffic (h, flags) via relaxed agent atomics (sc1 -> LLC).
// Release = h stores, s_waitcnt vmcnt(0), flag store. Acquire = in-order
// issue after poll + atomic (cache-bypassing) h loads. No cache-wide fences.
__global__ __launch_bounds__(512) void lstm_all(
    const unsigned short* __restrict__ WhT, const unsigned short* __restrict__ X,
    const float* __restrict__ bcomb, unsigned short* __restrict__ hb,
    int* __restrict__ flags, float* __restrict__ out) {
  __shared__ float xch[6][5][256];
  const int s = blockIdx.x;
  const int tid = threadIdx.x;
  const int wv = tid >> 6, lane = tid & 63;
  const int kh = wv >> 1, mh = wv & 1;
  const int l15 = lane & 15, kg = lane >> 4;

  // --- load this wave's weight fragments into registers (once) ---
  bf16x8 w[5][8];
#pragma unroll
  for (int g = 0; g < 5; ++g)
#pragma unroll
    for (int ks = 0; ks < 8; ++ks)
      w[g][ks] = *reinterpret_cast<const bf16x8*>(
          &WhT[(size_t)(s * 80 + g * 16 + l15) * Kd + kh * 256 + ks * 32 + kg * 8]);

  float bias[5] = {};
  float crg[4] = {0.f, 0.f, 0.f, 0.f}, cig[4] = {0.f, 0.f, 0.f, 0.f};
  if (kh == 0) {
#pragma unroll
    for (int g = 0; g < 5; ++g) bias[g] = bcomb[s * 80 + g * 16 + l15];
    // zero h slot 0 slice: rows [mh*16,+16), k in [s*32, s*32+32)
    int b = mh * 16 + (lane >> 2);
    int k0 = s * 32 + (lane & 3) * 8;
    unsigned int* p = (unsigned int*)&hb[(size_t)b * Kd + k0];
#pragma unroll
    for (int q = 0; q < 4; ++q) ast(&p[q], 0u);
    asm volatile("s_waitcnt vmcnt(0)" ::: "memory");
    if (lane == 0) ast((unsigned int*)&flags[mh * 32 + s], 1u);
  }

  const int fidx = mh * 32 + kh * 8 + (lane & 7);

  for (int t = 0; t < T_; ++t) {
    // prefetch X gate rows for the epilogue (independent of h -> before poll)
    unsigned short xvv[5][4];
    if (kh == 0) {
#pragma unroll
      for (int r = 0; r < 4; ++r) {
        int b = mh * 16 + kg * 4 + r;
        const unsigned short* xp = &X[((size_t)b * T_ + t) * Nd + s * 80 + l15];
#pragma unroll
        for (int g = 0; g < 5; ++g) xvv[g][r] = xp[g * 16];
      }
    }
    // wait for the 8 producer slabs of this wave's K quarter (same mh half)
    const unsigned int need = (unsigned int)(t + 1);
    while (true) {
      unsigned int v = ald((const unsigned int*)&flags[fidx]);
      if (__all(v >= need)) break;
    }
    asm volatile("" ::: "memory");  // compiler-only acquire

    const unsigned short* hin = hb + (size_t)(t % 3) * 32768;
    f32x4 acc[5] = {};
    union { bf16x8 v; unsigned int u[4]; } a[8];
#pragma unroll
    for (int ks = 0; ks < 8; ++ks) {
      const unsigned int* hp = (const unsigned int*)
          &hin[(size_t)(mh * 16 + l15) * Kd + kh * 256 + ks * 32 + kg * 8];
#pragma unroll
      for (int q = 0; q < 4; ++q) a[ks].u[q] = ald(&hp[q]);
    }
#pragma unroll
    for (int ks = 0; ks < 8; ++ks)
#pragma unroll
      for (int g = 0; g < 5; ++g)
        acc[g] = __builtin_amdgcn_mfma_f32_16x16x32_bf16(a[ks].v, w[g][ks], acc[g], 0, 0, 0);

    if (kh > 0) {
      int widx = (kh - 1) * 2 + mh;
#pragma unroll
      for (int g = 0; g < 5; ++g)
        *reinterpret_cast<f32x4*>(&xch[widx][g][lane * 4]) = acc[g];
    }
    __syncthreads();  // sync1: partials visible
    if (kh == 0) {
#pragma unroll
      for (int q = 0; q < 3; ++q)
#pragma unroll
        for (int g = 0; g < 5; ++g)
          acc[g] += *reinterpret_cast<const f32x4*>(&xch[q * 2 + mh][g][lane * 4]);
    }
    __syncthreads();  // sync2: xch free for next step (kh>0 waves run ahead)

    if (kh == 0) {
      unsigned short* hnext = hb + (size_t)((t + 1) % 3) * 32768;
      int hh = s * 16 + l15;
      float hrv[4], hiv[4], crv[4], civ[4];
#pragma unroll
      for (int r = 0; r < 4; ++r) {
        float pre[5];
#pragma unroll
        for (int g = 0; g < 5; ++g)
          pre[g] = acc[g][r] + bf_f(xvv[g][r]) + bias[g];
        float ig = fsig(pre[0]), fg = fsig(pre[1]), og = fsig(pre[2]);
        float ctr, cti; ctanh_(pre[3], pre[4], ctr, cti);
        float cr = fg * crg[r] + ig * ctr;
        float ci = fg * cig[r] + ig * cti;
        crg[r] = cr; cig[r] = ci;
        float hr0, hi0; ctanh_(cr, ci, hr0, hi0);
        hrv[r] = og * hr0; hiv[r] = og * hi0;
        crv[r] = cr; civ[r] = ci;
      }
      // critical path first: h stores -> vmcnt(0) -> flag
#pragma unroll
      for (int r = 0; r < 4; ++r) {
        int b = mh * 16 + kg * 4 + r;
        unsigned int hv = (unsigned int)f_bf(hrv[r]) | ((unsigned int)f_bf(hiv[r]) << 16);
        ast((unsigned int*)&hnext[(size_t)b * Kd + hh * 2], hv);
      }
      if (t < T_ - 1) {
        asm volatile("s_waitcnt vmcnt(0)" ::: "memory");
        if (lane == 0)
          ast((unsigned int*)&flags[mh * 32 + s], (unsigned int)(t + 2));
      }
      // private output traffic off the critical path
#pragma unroll
      for (int r = 0; r < 4; ++r) {
        int b = mh * 16 + kg * 4 + r;
        size_t oidx = ((size_t)b * T_ + t) * (Hd * 2) + hh * 2;
        *reinterpret_cast<float2*>(&out[oidx]) = make_float2(hrv[r], hiv[r]);
        if (t == T_ - 1) {
          size_t fb = HS_ELEMS + ((size_t)b * Hd + hh) * 2;
          *reinterpret_cast<float2*>(&out[fb]) = make_float2(hrv[r], hiv[r]);
          *reinterpret_cast<float2*>(&out[fb + 32768ull]) = make_float2(crv[r], civ[r]);
        }
      }
    }
  }
}

// ---------------------------------------------------------------------------
extern "C" void kernel_launch(void* const* d_in, const int* in_sizes, int n_in,
                              void* d_out, int out_size, void* d_ws, size_t ws_size,
                              hipStream_t stream) {
  const float* z   = (const float*)d_in[0];
  const float* Wzi = (const float*)d_in[1];
  const float* Whi = (const float*)d_in[2];
  const float* bi  = (const float*)d_in[3];
  const float* Wzf = (const float*)d_in[4];
  const float* Whf = (const float*)d_in[5];
  const float* bfv = (const float*)d_in[6];
  const float* Wzc = (const float*)d_in[7];
  const float* Whc = (const float*)d_in[8];
  const float* bc  = (const float*)d_in[9];
  const float* Wzo = (const float*)d_in[10];
  const float* Who = (const float*)d_in[11];
  const float* bo  = (const float*)d_in[12];
  float* out = (float*)d_out;

  size_t off = 0;
  char* ws = (char*)d_ws;
  auto take = [&](size_t nbytes) {
    void* p = ws + off; off += (nbytes + 255) & ~(size_t)255; return p;
  };
  unsigned short* WzT  = (unsigned short*)take((size_t)Nd * Kd * 2);
  unsigned short* WhT  = (unsigned short*)take((size_t)Nd * Kd * 2);
  float*          bcmb = (float*)take(Nd * 4);
  unsigned short* Z2   = (unsigned short*)take((size_t)Md * Kd * 2);
  unsigned short* X    = (unsigned short*)take((size_t)Md * Nd * 2);
  unsigned short* hb   = (unsigned short*)take(3 * 32768 * 2);
  int*            flags = (int*)take(64 * 4);

  hipMemsetAsync(flags, 0, 64 * 4, stream);
  build_weights<<<Nd, 256, 0, stream>>>(Wzi, Whi, bi, Wzf, Whf, bfv,
                                        Wzc, Whc, bc, Wzo, Who, bo,
                                        WzT, WhT, bcmb);
  cvt_z<<<8192, 256, 0, stream>>>((const float4*)z, (ushort4*)Z2);
  gemm_x<<<(Md / 128) * (Nd / 128), 256, 0, stream>>>(Z2, WzT, X);
  lstm_all<<<32, 512, 0, stream>>>(WhT, X, bcmb, hb, flags, out);
}

// Round 4
// 5163.718 us; speedup vs baseline: 2.6076x; 2.6076x over previous
//
#include <hip/hip_runtime.h>

// ComplexLSTMLayer: B=32, T=1024, I=512, H=512
// Phase 1: X = Z2 @ Wz_comb  (bf16 MFMA GEMM, M=32768, N=2560, K=1024)
// Phase 2: ONE persistent kernel, 32 WGs (one per 16-h slab) x 512 threads.
//   Weights in registers. X staged 8 steps ahead into LDS (keeps the flag
//   poll's vmcnt(0) clean). h/flag via relaxed agent atomics + asm sc1 loads.

#define B_ 32
#define T_ 1024
#define Hd 512
#define Kd 1024        // 2*I = 2*H
#define Nd 2560        // 5*H
#define Md 32768       // B*T
#define HS_ELEMS 33554432ull  // B*T*H*2

typedef __attribute__((ext_vector_type(8))) short bf16x8;
typedef __attribute__((ext_vector_type(4))) float f32x4;

__device__ __forceinline__ unsigned short f_bf(float f) {
  unsigned int x; __builtin_memcpy(&x, &f, 4);
  unsigned int r = (x + 0x7FFFu + ((x >> 16) & 1u)) >> 16;  // RNE
  return (unsigned short)r;
}
__device__ __forceinline__ float bf_f(unsigned short u) {
  unsigned int i = ((unsigned int)u) << 16; float f; __builtin_memcpy(&f, &i, 4); return f;
}
__device__ __forceinline__ float fsig(float x) { return 1.0f / (1.0f + __expf(-x)); }
__device__ __forceinline__ void ctanh_(float zr, float zi, float& tr, float& ti) {
  float m2 = zr * zr + zi * zi + 1e-14f;
  float mag = __fsqrt_rn(m2);          // >= 1e-7, the ref's max(.,1e-8) never binds
  float e = __expf(2.0f * mag);
  float th = 1.0f - 2.0f / (e + 1.0f); // tanh(mag)
  float s = th / mag;
  tr = zr * s; ti = zi * s;
}

__device__ __forceinline__ void gl16(const unsigned short* g, unsigned short* l) {
  __builtin_amdgcn_global_load_lds(
      (const __attribute__((address_space(1))) void*)g,
      (__attribute__((address_space(3))) void*)l, 16, 0, 0);
}

__device__ __forceinline__ unsigned int ald(const unsigned int* p) {
  return __hip_atomic_load(p, __ATOMIC_RELAXED, __HIP_MEMORY_SCOPE_AGENT);
}
__device__ __forceinline__ void ast(unsigned int* p, unsigned int v) {
  __hip_atomic_store(p, v, __ATOMIC_RELAXED, __HIP_MEMORY_SCOPE_AGENT);
}

// ---------------------------------------------------------------------------
// Combined transposed weights [n][k] bf16 + combined bias.
// n = slab*80 + g*16 + (h%16); k = 2*j + p (p: 0=re,1=im)
// gates g: 0=i,1=f,2=o,3=cr,4=ci. i/f/o/cr: (+W0, -W1); ci: (+W1, +W0).
__global__ void build_weights(const float* Wzi, const float* Whi, const float* bi,
                              const float* Wzf, const float* Whf, const float* bfv,
                              const float* Wzc, const float* Whc, const float* bc,
                              const float* Wzo, const float* Who, const float* bo,
                              unsigned short* WzT, unsigned short* WhT, float* bcomb) {
  int n = blockIdx.x;
  int slab = n / 80, wi = n % 80, g = wi / 16, hh = slab * 16 + (wi & 15);
  const float *Wz, *Wh;
  if (g == 0)      { Wz = Wzi; Wh = Whi; }
  else if (g == 1) { Wz = Wzf; Wh = Whf; }
  else if (g == 2) { Wz = Wzo; Wh = Who; }
  else             { Wz = Wzc; Wh = Whc; }
  int q0, q1; float s0, s1;
  if (g < 4) { q0 = 0; s0 = 1.f; q1 = 1; s1 = -1.f; }
  else       { q0 = 1; s0 = 1.f; q1 = 0; s1 =  1.f; }
  for (int k = threadIdx.x; k < Kd; k += 256) {
    int j = k >> 1, p = k & 1;
    int q = p ? q1 : q0; float sg = p ? s1 : s0;
    WzT[(size_t)n * Kd + k] = f_bf(sg * Wz[(j * Hd + hh) * 2 + q]);
    WhT[(size_t)n * Kd + k] = f_bf(sg * Wh[(j * Hd + hh) * 2 + q]);
  }
  if (threadIdx.x == 0) {
    float bv;
    if (g == 0) bv = bi[hh]; else if (g == 1) bv = bfv[hh];
    else if (g == 2) bv = bo[hh];
    else if (g == 3) bv = bc[2 * hh]; else bv = bc[2 * hh + 1];
    bcomb[n] = bv;
  }
}

__global__ void cvt_z(const float4* __restrict__ z, ushort4* __restrict__ Z2) {
  for (size_t i = (size_t)blockIdx.x * 256 + threadIdx.x; i < 8388608ull; i += 8192ull * 256) {
    float4 v = z[i];
    ushort4 o;
    o.x = f_bf(v.x); o.y = f_bf(v.y); o.z = f_bf(v.z); o.w = f_bf(v.w);
    Z2[i] = o;
  }
}

// ---------------------------------------------------------------------------
// Phase-1 GEMM: X[m][n] = sum_k Z2[m][k] * WT[n][k]. bf16 out. (verified r1)
__global__ __launch_bounds__(256) void gemm_x(const unsigned short* __restrict__ Z2,
                                              const unsigned short* __restrict__ WT,
                                              unsigned short* __restrict__ X) {
  __shared__ unsigned short As[128 * 64];
  __shared__ unsigned short Bs[128 * 64];
  int tid = threadIdx.x, lane = tid & 63, wv = tid >> 6;
  int bid = blockIdx.x;
  int mb = bid / (Nd / 128), nb = bid % (Nd / 128);
  size_t m0 = (size_t)mb * 128, n0 = (size_t)nb * 128;
  int wr = wv >> 1, wc = wv & 1;
  int l15 = lane & 15, kg = lane >> 4;
  int lrow = tid >> 3;
  int lcol = (tid & 7) * 8;
  f32x4 acc[4][4] = {};
  for (int k0 = 0; k0 < Kd; k0 += 64) {
    __syncthreads();
#pragma unroll
    for (int c = 0; c < 4; ++c) {
      gl16(Z2 + (m0 + c * 32 + lrow) * Kd + k0 + lcol,
           As + (size_t)c * 2048 + wv * 512);
      gl16(WT + (n0 + c * 32 + lrow) * Kd + k0 + lcol,
           Bs + (size_t)c * 2048 + wv * 512);
    }
    __syncthreads();
#pragma unroll
    for (int ks = 0; ks < 2; ++ks) {
      int kk = ks * 32 + kg * 8;
      bf16x8 a[4], b[4];
#pragma unroll
      for (int i = 0; i < 4; ++i)
        a[i] = *reinterpret_cast<const bf16x8*>(&As[(wr * 64 + i * 16 + l15) * 64 + kk]);
#pragma unroll
      for (int j = 0; j < 4; ++j)
        b[j] = *reinterpret_cast<const bf16x8*>(&Bs[(wc * 64 + j * 16 + l15) * 64 + kk]);
#pragma unroll
      for (int i = 0; i < 4; ++i)
#pragma unroll
        for (int j = 0; j < 4; ++j)
          acc[i][j] = __builtin_amdgcn_mfma_f32_16x16x32_bf16(a[i], b[j], acc[i][j], 0, 0, 0);
    }
  }
#pragma unroll
  for (int i = 0; i < 4; ++i)
#pragma unroll
    for (int j = 0; j < 4; ++j) {
      size_t gm = m0 + wr * 64 + i * 16 + kg * 4;
      size_t gn = n0 + wc * 64 + j * 16 + l15;
#pragma unroll
      for (int r = 0; r < 4; ++r)
        X[(gm + r) * Nd + gn] = f_bf(acc[i][j][r]);
    }
}

// ---------------------------------------------------------------------------
// Persistent recurrence. WG s owns h-slab [s*16,(s+1)*16). 8 waves:
//   MFMA role: kh = wv>>1 (K quarter), mh = wv&1 (batch half).
//   Epilogue role: lane-cell tid -> (b = tid>>4, hh16 = tid&15).
// X staged 8 steps ahead into LDS (gl16, vmcnt-quiet per-step via ds_read).
// h loads: asm global_load_dwordx4 sc0 sc1 (LLC-fresh, wide).
// One flag per slab, posted after all-wave store-ack + barrier.
#define CHUNK 8
#define STEPB (Nd * 2)          // bytes per step-slab in LDS: 32*80*2 = 5120
__global__ __launch_bounds__(512) void lstm_all(
    const unsigned short* __restrict__ WhT, const unsigned short* __restrict__ X,
    const float* __restrict__ bcomb, unsigned short* __restrict__ hb,
    int* __restrict__ flags, float* __restrict__ out) {
  __shared__ unsigned short Xs[2][CHUNK * STEPB / 2];  // 2 x 40960B
  __shared__ float xch[8][5][256];                     // 40KB
  const int s = blockIdx.x;
  const int tid = threadIdx.x;
  const int wv = tid >> 6, lane = tid & 63;
  const int kh = wv >> 1, mh = wv & 1;
  const int l15 = lane & 15, kg = lane >> 4;
  const int cb = tid >> 4;        // epilogue cell: batch 0..31
  const int ch = tid & 15;        // epilogue cell: h within slab
  const int hh = s * 16 + ch;

  // --- stage X chunk 0 (steps 0..7): 40 wave-instrs, 5 per wave ---
  auto stage = [&](int tbase, int buf) {
#pragma unroll
    for (int j = 0; j < 5; ++j) {
      unsigned int P = (unsigned int)(wv * 5 + j) * 1024u + (unsigned int)lane * 16u;
      unsigned int st = P / STEPB, r = P % STEPB;
      unsigned int b = r / 160u, rem = r % 160u;
      gl16(X + ((size_t)b * T_ + (tbase + st)) * Nd + s * 80 + rem / 2,
           &Xs[buf][(size_t)(wv * 5 + j) * 512]);
    }
  };
  stage(0, 0);

  // --- weights into registers ---
  bf16x8 w[5][8];
#pragma unroll
  for (int g = 0; g < 5; ++g)
#pragma unroll
    for (int ks = 0; ks < 8; ++ks)
      w[g][ks] = *reinterpret_cast<const bf16x8*>(
          &WhT[(size_t)(s * 80 + g * 16 + l15) * Kd + kh * 256 + ks * 32 + kg * 8]);

  float bias[5];
#pragma unroll
  for (int g = 0; g < 5; ++g) bias[g] = bcomb[s * 80 + g * 16 + ch];
  float cr = 0.f, ci = 0.f;

  // zero h slot 0 (this WG's slab columns, all 32 batches: one dword/lane)
  ast((unsigned int*)hb + (size_t)cb * 512 + s * 16 + ch, 0u);
  asm volatile("s_waitcnt vmcnt(0)" ::: "memory");
  __syncthreads();
  if (tid == 0) ast((unsigned int*)&flags[s], 1u);

  const int fidx = kh * 8 + (lane & 7);
  const int mb = cb >> 4;
  const int xidx = ((cb & 15) >> 2) * 64 + ch * 4 + (cb & 3);

  for (int t = 0; t < T_; ++t) {
    // wait for the 8 producer slabs of this wave's K quarter
    const unsigned int need = (unsigned int)(t + 1);
    while (true) {
      unsigned int v = ald((const unsigned int*)&flags[fidx]);
      if (__all(v >= need)) break;
    }
    asm volatile("" ::: "memory");  // compiler-only acquire

    // h fragment loads: LLC-fresh wide loads
    const unsigned short* hin = hb + (size_t)(t % 3) * 32768;
    unsigned long long hpa = (unsigned long long)(
        hin + (size_t)(mh * 16 + l15) * Kd + kh * 256 + kg * 8);
    bf16x8 a[8];
#define HL(i, off) asm volatile("global_load_dwordx4 %0, %1, off offset:" #off " sc0 sc1" \
                                 : "=v"(a[i]) : "v"(hpa) : "memory")
    HL(0, 0); HL(1, 64); HL(2, 128); HL(3, 192);
    HL(4, 256); HL(5, 320); HL(6, 384); HL(7, 448);
#undef HL
    asm volatile("s_waitcnt vmcnt(0)" ::: "memory");
    __builtin_amdgcn_sched_barrier(0);

    // prefetch next X chunk (issued after the vmcnt-clean point)
    if ((t & (CHUNK - 1)) == 0 && t + CHUNK < T_)
      stage(t + CHUNK, ((t >> 3) + 1) & 1);

    f32x4 acc[5] = {};
#pragma unroll
    for (int ks = 0; ks < 8; ++ks)
#pragma unroll
      for (int g = 0; g < 5; ++g)
        acc[g] = __builtin_amdgcn_mfma_f32_16x16x32_bf16(a[ks], w[g][ks], acc[g], 0, 0, 0);

    // all waves publish partials
#pragma unroll
    for (int g = 0; g < 5; ++g)
      *reinterpret_cast<f32x4*>(&xch[wv][g][lane * 4]) = acc[g];
    __syncthreads();  // sync1

    // per-lane cell epilogue: reduce 4 k-quarters + X + bias
    const unsigned short* xsl = &Xs[(t >> 3) & 1][(t & 7) * Nd + cb * 80 + ch];
    float pre[5];
#pragma unroll
    for (int g = 0; g < 5; ++g) {
      float p = bias[g] + bf_f(xsl[g * 16]);
#pragma unroll
      for (int q = 0; q < 4; ++q) p += xch[q * 2 + mb][g][xidx];
      pre[g] = p;
    }
    float ig = fsig(pre[0]), fg = fsig(pre[1]), og = fsig(pre[2]);
    float ctr, cti; ctanh_(pre[3], pre[4], ctr, cti);
    cr = fg * cr + ig * ctr;
    ci = fg * ci + ig * cti;
    float hr0, hi0; ctanh_(cr, ci, hr0, hi0);
    float hr = og * hr0, hi = og * hi0;

    // h store -> ack -> barrier -> flag
    unsigned short* hnext = hb + (size_t)((t + 1) % 3) * 32768;
    unsigned int hv = (unsigned int)f_bf(hr) | ((unsigned int)f_bf(hi) << 16);
    ast((unsigned int*)hnext + (size_t)cb * 512 + s * 16 + ch, hv);
    if (t < T_ - 1) {
      asm volatile("s_waitcnt vmcnt(0)" ::: "memory");
      __syncthreads();
      if (tid == 0) ast((unsigned int*)&flags[s], (unsigned int)(t + 2));
    }

    // private outputs (off the critical path)
    size_t oidx = ((size_t)cb * T_ + t) * (Hd * 2) + hh * 2;
    *reinterpret_cast<float2*>(&out[oidx]) = make_float2(hr, hi);
    if (t == T_ - 1) {
      size_t fb = HS_ELEMS + ((size_t)cb * Hd + hh) * 2;
      *reinterpret_cast<float2*>(&out[fb]) = make_float2(hr, hi);
      *reinterpret_cast<float2*>(&out[fb + 32768ull]) = make_float2(cr, ci);
    }
  }
}

// ---------------------------------------------------------------------------
extern "C" void kernel_launch(void* const* d_in, const int* in_sizes, int n_in,
                              void* d_out, int out_size, void* d_ws, size_t ws_size,
                              hipStream_t stream) {
  const float* z   = (const float*)d_in[0];
  const float* Wzi = (const float*)d_in[1];
  const float* Whi = (const float*)d_in[2];
  const float* bi  = (const float*)d_in[3];
  const float* Wzf = (const float*)d_in[4];
  const float* Whf = (const float*)d_in[5];
  const float* bfv = (const float*)d_in[6];
  const float* Wzc = (const float*)d_in[7];
  const float* Whc = (const float*)d_in[8];
  const float* bc  = (const float*)d_in[9];
  const float* Wzo = (const float*)d_in[10];
  const float* Who = (const float*)d_in[11];
  const float* bo  = (const float*)d_in[12];
  float* out = (float*)d_out;

  size_t off = 0;
  char* ws = (char*)d_ws;
  auto take = [&](size_t nbytes) {
    void* p = ws + off; off += (nbytes + 255) & ~(size_t)255; return p;
  };
  unsigned short* WzT  = (unsigned short*)take((size_t)Nd * Kd * 2);
  unsigned short* WhT  = (unsigned short*)take((size_t)Nd * Kd * 2);
  float*          bcmb = (float*)take(Nd * 4);
  unsigned short* Z2   = (unsigned short*)take((size_t)Md * Kd * 2);
  unsigned short* X    = (unsigned short*)take((size_t)Md * Nd * 2);
  unsigned short* hb   = (unsigned short*)take(3 * 32768 * 2);
  int*            flags = (int*)take(64 * 4);

  hipMemsetAsync(flags, 0, 64 * 4, stream);
  build_weights<<<Nd, 256, 0, stream>>>(Wzi, Whi, bi, Wzf, Whf, bfv,
                                        Wzc, Whc, bc, Wzo, Who, bo,
                                        WzT, WhT, bcmb);
  cvt_z<<<8192, 256, 0, stream>>>((const float4*)z, (ushort4*)Z2);
  gemm_x<<<(Md / 128) * (Nd / 128), 256, 0, stream>>>(Z2, WzT, X);
  lstm_all<<<32, 512, 0, stream>>>(WhT, X, bcmb, hb, flags, out);
}